// Round 3
// baseline (402.733 us; speedup 1.0000x reference)
//
#include <hip/hip_runtime.h>

// YOLOv1 loss, pred/labels (B,30,7,7) fp32 -> scalar.
// R2: latency-bound at 23% HBM (59 scalar loads/thread, 40 VGPRs).
// R3: stage 4 images/block (pred+labels = 47 KB LDS) via coalesced float4
//     flat loads; compute per-cell from LDS. 3 blocks/CU by LDS.

#define GRID 7
#define NCH 30
#define CPI (GRID * GRID)        // 49 cells per image
#define IMG 4                    // images per block
#define FPI (NCH * CPI)          // 1470 floats per image per tensor
#define F4PB (IMG * FPI / 4)     // 1470 float4 per tensor per block (5880 floats)

__device__ __forceinline__ float iou_xyxy(float x1a, float y1a, float x2a, float y2a,
                                          float x1b, float y1b, float x2b, float y2b) {
    float iw = fmaxf(fminf(x2a, x2b) - fmaxf(x1a, x1b), 0.0f);
    float ih = fmaxf(fminf(y2a, y2b) - fmaxf(y1a, y1b), 0.0f);
    float inter = iw * ih;
    float a1 = (x2a - x1a) * (y2a - y1a);
    float a2 = (x2b - x1b) * (y2b - y1b);
    float uni = a1 + a2 - inter;
    return inter > 0.0f ? inter / uni : 0.0f;
}

__global__ void __launch_bounds__(256) yolo_loss_kernel(
        const float* __restrict__ pred,
        const float* __restrict__ labels,
        float* __restrict__ out,
        float invB) {
    __shared__ float4 smem[2 * F4PB];   // pred[0..F4PB) labels[F4PB..2*F4PB) = 47040 B

    // ---- stage 4 images of pred + labels, fully coalesced 16 B/lane ----
    const float4* pg = (const float4*)pred   + (size_t)blockIdx.x * F4PB;
    const float4* lg = (const float4*)labels + (size_t)blockIdx.x * F4PB;
    #pragma unroll
    for (int i = threadIdx.x; i < 2 * F4PB; i += 256) {
        smem[i] = (i < F4PB) ? pg[i] : lg[i - F4PB];
    }
    __syncthreads();

    // ---- compute: one cell per thread, 196 cells per block ----
    float acc = 0.0f;
    int t = threadIdx.x;
    if (t < IMG * CPI) {
        int img = t / CPI;
        int cell = t - img * CPI;
        int m = cell / GRID;          // dim-2 index, pairs with x
        int n = cell - m * GRID;      // dim-3 index, pairs with y

        const float* pb = (const float*)smem + img * FPI + cell;
        const float* lb = (const float*)smem + IMG * FPI + img * FPI + cell;

        float p0 = pb[0 * CPI], p1 = pb[1 * CPI], p2 = pb[2 * CPI], p3 = pb[3 * CPI];
        float p4 = pb[4 * CPI], p5 = pb[5 * CPI], p6 = pb[6 * CPI], p7 = pb[7 * CPI];
        float p8 = pb[8 * CPI], p9 = pb[9 * CPI];
        float l0 = lb[0 * CPI], l1 = lb[1 * CPI], l2 = lb[2 * CPI], l3 = lb[3 * CPI];
        float lobj = lb[4 * CPI];
        float l5 = lb[5 * CPI], l6 = lb[6 * CPI], l7 = lb[7 * CPI], l8 = lb[8 * CPI];

        float cls = 0.0f;
        #pragma unroll
        for (int c = 10; c < NCH; ++c) {
            float d = pb[c * CPI] - lb[c * CPI];
            cls += d * d;
        }

        const float inv_g = 1.0f / (float)GRID;
        float fm = (float)m, fn = (float)n;

        float cx = (p0 + fm) * inv_g, cy = (p1 + fn) * inv_g;
        float b1x1 = cx - p2 * 0.5f, b1y1 = cy - p3 * 0.5f;
        float b1x2 = cx + p2 * 0.5f, b1y2 = cy + p3 * 0.5f;
        cx = (p5 + fm) * inv_g; cy = (p6 + fn) * inv_g;
        float b2x1 = cx - p7 * 0.5f, b2y1 = cy - p8 * 0.5f;
        float b2x2 = cx + p7 * 0.5f, b2y2 = cy + p8 * 0.5f;
        cx = (l0 + fm) * inv_g; cy = (l1 + fn) * inv_g;
        float gx1 = cx - l2 * 0.5f, gy1 = cy - l3 * 0.5f;
        float gx2 = cx + l2 * 0.5f, gy2 = cy + l3 * 0.5f;

        float iou1 = iou_xyxy(b1x1, b1y1, b1x2, b1y2, gx1, gy1, gx2, gy2);
        float iou2 = iou_xyxy(b2x1, b2y1, b2x2, b2y2, gx1, gy1, gx2, gy2);
        bool resp1 = iou1 >= iou2;

        float dx = p0 - l0, dy = p1 - l1;
        float dw = sqrtf(p2) - sqrtf(l2), dh = sqrtf(p3) - sqrtf(l3);
        float coor1 = 5.0f * (dx * dx + dy * dy + dw * dw + dh * dh);
        dx = p5 - l5; dy = p6 - l6;
        dw = sqrtf(p7) - sqrtf(l7); dh = sqrtf(p8) - sqrtf(l8);
        float coor2 = 5.0f * (dx * dx + dy * dy + dw * dw + dh * dh);

        float e1 = p4 - iou1, e2 = p9 - iou2;
        float loss_b1 = coor1 + e1 * e1 + 0.5f * e2 * e2;
        float loss_b2 = coor2 + e2 * e2 + 0.5f * e1 * e1;

        float obj_loss = (resp1 ? loss_b1 : loss_b2) + cls;
        float noobj_loss = 0.5f * (p4 * p4 + p9 * p9);

        float contrib = (lobj == 1.0f) ? obj_loss : noobj_loss;
        acc = contrib * invB;
    }

    // ---- block reduction: wave shuffle -> LDS -> one atomic ----
    #pragma unroll
    for (int off = 32; off > 0; off >>= 1)
        acc += __shfl_down(acc, off, 64);

    __shared__ float rsm[4];
    int lane = threadIdx.x & 63;
    int wid = threadIdx.x >> 6;
    if (lane == 0) rsm[wid] = acc;
    __syncthreads();
    if (threadIdx.x == 0) {
        float v = rsm[0] + rsm[1] + rsm[2] + rsm[3];
        atomicAdd(out, v);
    }
}

extern "C" void kernel_launch(void* const* d_in, const int* in_sizes, int n_in,
                              void* d_out, int out_size, void* d_ws, size_t ws_size,
                              hipStream_t stream) {
    const float* pred = (const float*)d_in[0];
    const float* labels = (const float*)d_in[1];
    float* out = (float*)d_out;

    int total = in_sizes[0];
    int B = total / FPI;             // 32768
    int nblocks = B / IMG;           // 8192

    hipMemsetAsync(out, 0, sizeof(float), stream);
    yolo_loss_kernel<<<nblocks, 256, 0, stream>>>(pred, labels, out, 1.0f / (float)B);
}

// Round 4
// 385.230 us; speedup vs baseline: 1.0454x; 1.0454x over previous
//
#include <hip/hip_runtime.h>

// YOLOv1 loss, pred/labels (B,30,7,7) fp32 -> scalar.
// R2: 137us, 23% HBM, VALUBusy 10% — NOT load-latency bound (R3 LDS staging
//     made it worse). Theory: 6-8k same-address atomicAdds serialize (~100us).
// R4: two-stage reduction — 2048 blocks write partials to d_ws (no atomics),
//     1-block final kernel sums them. Direct scalar loads, grid-stride.

#define GRID 7
#define NCH 30
#define CPI (GRID * GRID)        // 49 cells per image
#define FPI (NCH * CPI)          // 1470 floats per image
#define NBLK 2048

__device__ __forceinline__ float iou_xyxy(float x1a, float y1a, float x2a, float y2a,
                                          float x1b, float y1b, float x2b, float y2b) {
    float iw = fmaxf(fminf(x2a, x2b) - fmaxf(x1a, x1b), 0.0f);
    float ih = fmaxf(fminf(y2a, y2b) - fmaxf(y1a, y1b), 0.0f);
    float inter = iw * ih;
    float a1 = (x2a - x1a) * (y2a - y1a);
    float a2 = (x2b - x1b) * (y2b - y1b);
    float uni = a1 + a2 - inter;
    return inter > 0.0f ? inter / uni : 0.0f;
}

__global__ void __launch_bounds__(256) yolo_partial_kernel(
        const float* __restrict__ pred,
        const float* __restrict__ labels,
        float* __restrict__ partials,
        int ncells, float invB) {
    float acc = 0.0f;
    int stride = gridDim.x * blockDim.x;
    for (int idx = blockIdx.x * blockDim.x + threadIdx.x; idx < ncells; idx += stride) {
        int b = idx / CPI;
        int cell = idx - b * CPI;
        int m = cell / GRID;          // dim-2 index, pairs with x
        int n = cell - m * GRID;      // dim-3 index, pairs with y

        const float* pb = pred   + (size_t)b * FPI + cell;
        const float* lb = labels + (size_t)b * FPI + cell;

        float p0 = pb[0 * CPI], p1 = pb[1 * CPI], p2 = pb[2 * CPI], p3 = pb[3 * CPI];
        float p4 = pb[4 * CPI], p5 = pb[5 * CPI], p6 = pb[6 * CPI], p7 = pb[7 * CPI];
        float p8 = pb[8 * CPI], p9 = pb[9 * CPI];
        float l0 = lb[0 * CPI], l1 = lb[1 * CPI], l2 = lb[2 * CPI], l3 = lb[3 * CPI];
        float lobj = lb[4 * CPI];
        float l5 = lb[5 * CPI], l6 = lb[6 * CPI], l7 = lb[7 * CPI], l8 = lb[8 * CPI];

        float cls = 0.0f;
        #pragma unroll
        for (int c = 10; c < NCH; ++c) {
            float d = pb[c * CPI] - lb[c * CPI];
            cls += d * d;
        }

        const float inv_g = 1.0f / (float)GRID;
        float fm = (float)m, fn = (float)n;

        float cx = (p0 + fm) * inv_g, cy = (p1 + fn) * inv_g;
        float b1x1 = cx - p2 * 0.5f, b1y1 = cy - p3 * 0.5f;
        float b1x2 = cx + p2 * 0.5f, b1y2 = cy + p3 * 0.5f;
        cx = (p5 + fm) * inv_g; cy = (p6 + fn) * inv_g;
        float b2x1 = cx - p7 * 0.5f, b2y1 = cy - p8 * 0.5f;
        float b2x2 = cx + p7 * 0.5f, b2y2 = cy + p8 * 0.5f;
        cx = (l0 + fm) * inv_g; cy = (l1 + fn) * inv_g;
        float gx1 = cx - l2 * 0.5f, gy1 = cy - l3 * 0.5f;
        float gx2 = cx + l2 * 0.5f, gy2 = cy + l3 * 0.5f;

        float iou1 = iou_xyxy(b1x1, b1y1, b1x2, b1y2, gx1, gy1, gx2, gy2);
        float iou2 = iou_xyxy(b2x1, b2y1, b2x2, b2y2, gx1, gy1, gx2, gy2);
        bool resp1 = iou1 >= iou2;

        float dx = p0 - l0, dy = p1 - l1;
        float dw = sqrtf(p2) - sqrtf(l2), dh = sqrtf(p3) - sqrtf(l3);
        float coor1 = 5.0f * (dx * dx + dy * dy + dw * dw + dh * dh);
        dx = p5 - l5; dy = p6 - l6;
        dw = sqrtf(p7) - sqrtf(l7); dh = sqrtf(p8) - sqrtf(l8);
        float coor2 = 5.0f * (dx * dx + dy * dy + dw * dw + dh * dh);

        float e1 = p4 - iou1, e2 = p9 - iou2;
        float loss_b1 = coor1 + e1 * e1 + 0.5f * e2 * e2;
        float loss_b2 = coor2 + e2 * e2 + 0.5f * e1 * e1;

        float obj_loss = (resp1 ? loss_b1 : loss_b2) + cls;
        float noobj_loss = 0.5f * (p4 * p4 + p9 * p9);

        acc += ((lobj == 1.0f) ? obj_loss : noobj_loss) * invB;
    }

    // block reduction: wave shuffle -> LDS -> one partial write (no atomics)
    #pragma unroll
    for (int off = 32; off > 0; off >>= 1)
        acc += __shfl_down(acc, off, 64);

    __shared__ float rsm[4];
    int lane = threadIdx.x & 63;
    int wid = threadIdx.x >> 6;
    if (lane == 0) rsm[wid] = acc;
    __syncthreads();
    if (threadIdx.x == 0)
        partials[blockIdx.x] = rsm[0] + rsm[1] + rsm[2] + rsm[3];
}

__global__ void __launch_bounds__(256) yolo_final_kernel(
        const float* __restrict__ partials, float* __restrict__ out, int n) {
    float acc = 0.0f;
    for (int i = threadIdx.x; i < n; i += 256)
        acc += partials[i];
    #pragma unroll
    for (int off = 32; off > 0; off >>= 1)
        acc += __shfl_down(acc, off, 64);
    __shared__ float rsm[4];
    int lane = threadIdx.x & 63;
    int wid = threadIdx.x >> 6;
    if (lane == 0) rsm[wid] = acc;
    __syncthreads();
    if (threadIdx.x == 0)
        out[0] = rsm[0] + rsm[1] + rsm[2] + rsm[3];
}

extern "C" void kernel_launch(void* const* d_in, const int* in_sizes, int n_in,
                              void* d_out, int out_size, void* d_ws, size_t ws_size,
                              hipStream_t stream) {
    const float* pred = (const float*)d_in[0];
    const float* labels = (const float*)d_in[1];
    float* out = (float*)d_out;
    float* partials = (float*)d_ws;    // NBLK floats

    int total = in_sizes[0];
    int B = total / FPI;               // 32768
    int ncells = B * CPI;              // 1,605,632

    yolo_partial_kernel<<<NBLK, 256, 0, stream>>>(pred, labels, partials,
                                                  ncells, 1.0f / (float)B);
    yolo_final_kernel<<<1, 256, 0, stream>>>(partials, out, NBLK);
}